// Round 5
// baseline (5638.982 us; speedup 1.0000x reference)
//
#include <hip/hip_runtime.h>
#include <math.h>

#define DEV __device__ __forceinline__

typedef unsigned short ushort_t;
typedef __attribute__((ext_vector_type(8))) short s8v;    // 8 x bf16
typedef __attribute__((ext_vector_type(4))) float f4v;    // MFMA acc

DEV float sp_(float x){ float m=fmaxf(x,0.f); return m + log1pf(expf(-fabsf(x))); }
DEV float sig_(float x){ return 1.f/(1.f+expf(-x)); }
DEV float kld_(float m1,float s1,float m2,float s2){
  float d=m1-m2;
  return 2.f*(logf(s2)-logf(s1)) + (s1*s1+d*d)/(s2*s2) - 1.f;
}
DEV unsigned short f2bf(float x){
  unsigned u = __float_as_uint(x);
  u += 0x7FFFu + ((u>>16)&1u);
  return (unsigned short)(u>>16);
}

DEV float blockReduceSum(float v){
  __shared__ float sh[8];
  #pragma unroll
  for(int o=32;o>0;o>>=1) v += __shfl_down(v,o,64);
  int lane = threadIdx.x & 63, wid = threadIdx.x >> 6;
  if(lane==0) sh[wid]=v;
  __syncthreads();
  float r = 0.f;
  if(threadIdx.x < (int)(blockDim.x>>6)) r = sh[threadIdx.x];
  if(wid==0){
    #pragma unroll
    for(int o=4;o>0;o>>=1) r += __shfl_down(r,o,64);
  }
  return r;
}

// ==================== MFMA bf16 GEMM, double-buffered ====================
// C = epilogue( A @ B ); A = virtual K-concat [A1|A2] fp32 -> bf16 on the fly.
// Optional A-transform (epsP): a = a + eps*softplus(a)  (zt reparam; K2 must be 0).
// Optional KLD fold (kldS, block-col 0 only): accumulates
//   0.5*sum(kld_e(m1, sp(m1), m2, sp(m2))) where m2 = A1[row][K1 + k] (pri cols).
// BT bf16 [N][ldbt] covers the FULL concat K. Cadd applied to cols < cadd_cols.
// M%64==0, Kt%32==0, K1%8==0.
__global__ __launch_bounds__(256)
void gemm_mf(const float* __restrict__ A1, int lda1, int K1,
             const float* __restrict__ A2, int lda2, int K2,
             const ushort_t* __restrict__ BT, int ldbt,
             const float* __restrict__ bias,
             const float* __restrict__ Cadd, int rowmask, int ldcadd, int cadd_cols,
             float* __restrict__ Cm, int ldc, int N, int relu_cut,
             const float* __restrict__ epsP, float* __restrict__ kldS)
{
  __shared__ ushort_t As[2][64][40];
  __shared__ ushort_t Bs[2][64][40];
  const int tid  = threadIdx.x;
  const int row0 = blockIdx.y * 64;
  const int col0 = blockIdx.x * 64;
  const int lane = tid & 63;
  const int w    = tid >> 6;
  const int wr   = w >> 1, wc = w & 1;
  const int Kt   = K1 + K2;
  const int nk   = Kt >> 5;
  const int sr   = tid >> 2;
  const int skc  = (tid & 3) * 8;
  const bool dokld = (kldS != 0) && (blockIdx.x == 0);
  float kloc = 0.f;
  float fa[8];
  s8v breg;

  f4v acc[2][2];
  #pragma unroll
  for(int i=0;i<2;i++){
    #pragma unroll
    for(int j=0;j<2;j++){ acc[i][j][0]=0.f; acc[i][j][1]=0.f; acc[i][j][2]=0.f; acc[i][j][3]=0.f; }
  }

  auto loadrg = [&](int it){
    int kg = it*32 + skc;
    const float* ap = (kg < K1) ? (A1 + (size_t)(row0+sr)*lda1 + kg)
                                : (A2 + (size_t)(row0+sr)*lda2 + (kg-K1));
    float4 v0 = *(const float4*)ap;
    float4 v1 = *(const float4*)(ap+4);
    fa[0]=v0.x; fa[1]=v0.y; fa[2]=v0.z; fa[3]=v0.w;
    fa[4]=v1.x; fa[5]=v1.y; fa[6]=v1.z; fa[7]=v1.w;
    if(dokld){
      const float* pp = A1 + (size_t)(row0+sr)*lda1 + K1 + kg;
      float4 p0 = *(const float4*)pp;
      float4 p1 = *(const float4*)(pp+4);
      float fp[8] = {p0.x,p0.y,p0.z,p0.w,p1.x,p1.y,p1.z,p1.w};
      #pragma unroll
      for(int j=0;j<8;j++){
        float m1=fa[j], m2=fp[j];
        kloc += kld_(m1, sp_(m1), m2, sp_(m2));
      }
    }
    if(epsP){
      const float* ep = epsP + (size_t)(row0+sr)*K1 + kg;
      #pragma unroll
      for(int j=0;j<8;j++) fa[j] = fmaf(ep[j], sp_(fa[j]), fa[j]);
    }
    int cb = col0 + sr;
    s8v bz = {0,0,0,0,0,0,0,0};
    breg = bz;
    if(cb < N) breg = *(const s8v*)(BT + (size_t)cb*ldbt + kg);
  };
  auto writeb = [&](int buf){
    s8v av;
    #pragma unroll
    for(int j=0;j<8;j++) av[j] = (short)f2bf(fa[j]);
    *(s8v*)&As[buf][sr][skc] = av;
    *(s8v*)&Bs[buf][sr][skc] = breg;
  };

  loadrg(0); writeb(0);
  __syncthreads();
  for(int it=0; it<nk; ++it){
    int cur = it & 1;
    bool more = (it+1) < nk;
    if(more) loadrg(it+1);
    const int fr = lane & 15, fk = (lane >> 4) * 8;
    s8v a0 = *(const s8v*)&As[cur][wr*32      + fr][fk];
    s8v a1 = *(const s8v*)&As[cur][wr*32 + 16 + fr][fk];
    s8v b0 = *(const s8v*)&Bs[cur][wc*32      + fr][fk];
    s8v b1 = *(const s8v*)&Bs[cur][wc*32 + 16 + fr][fk];
    acc[0][0] = __builtin_amdgcn_mfma_f32_16x16x32_bf16(a0,b0,acc[0][0],0,0,0);
    acc[0][1] = __builtin_amdgcn_mfma_f32_16x16x32_bf16(a0,b1,acc[0][1],0,0,0);
    acc[1][0] = __builtin_amdgcn_mfma_f32_16x16x32_bf16(a1,b0,acc[1][0],0,0,0);
    acc[1][1] = __builtin_amdgcn_mfma_f32_16x16x32_bf16(a1,b1,acc[1][1],0,0,0);
    if(more) writeb(cur^1);
    __syncthreads();
  }

  if(kldS && blockIdx.x==0){
    float tot = blockReduceSum(kloc);
    if(tid==0) atomicAdd(kldS, 0.5f*tot);
  }

  const int fr = lane & 15, fq = lane >> 4;
  #pragma unroll
  for(int fi=0; fi<2; fi++){
    #pragma unroll
    for(int fj=0; fj<2; fj++){
      int col = col0 + wc*32 + fj*16 + fr;
      if(col >= N) continue;
      #pragma unroll
      for(int r=0;r<4;r++){
        int row = row0 + wr*32 + fi*16 + fq*4 + r;
        float v = acc[fi][fj][r];
        if(Cadd && col < cadd_cols) v += Cadd[(size_t)(row & rowmask)*ldcadd + col];
        if(bias) v += bias[col];
        if(col < relu_cut) v = fmaxf(v, 0.f);
        Cm[(size_t)row*ldc + col] = v;
      }
    }
  }
}

// ==================== fused GI-GEMM + GRU update ====================
// Computes gi = [A1|A2] @ Wih (3 gates, channels Hd) (+bias)(+Cadd, ld ldcadd),
// then h = (1-u)*n + u*h with gh read from GHp (ld ldgh). Writes Hp in place.
// grid = (Hd/64, M/64). BT rows: gate g channel c -> row g*Hd + c.
__global__ __launch_bounds__(256)
void gemm_gru(const float* __restrict__ A1, int lda1, int K1,
              const float* __restrict__ A2, int lda2, int K2,
              const ushort_t* __restrict__ BT, int ldbt,
              const float* __restrict__ bias,
              const float* __restrict__ Cadd, int ldcadd,
              const float* __restrict__ GHp, int ldgh,
              float* __restrict__ Hp, int Hd)
{
  __shared__ ushort_t As[2][64][40];
  __shared__ ushort_t Bs[2][3][64][40];
  const int tid  = threadIdx.x;
  const int row0 = blockIdx.y * 64;
  const int col0 = blockIdx.x * 64;
  const int lane = tid & 63;
  const int w    = tid >> 6;
  const int wr   = w >> 1, wc = w & 1;
  const int Kt   = K1 + K2;
  const int nk   = Kt >> 5;
  const int sr   = tid >> 2;
  const int skc  = (tid & 3) * 8;
  float fa[8];
  s8v bregs[3];

  f4v acc[3][2][2];
  #pragma unroll
  for(int g=0;g<3;g++){
    #pragma unroll
    for(int i=0;i<2;i++){
      #pragma unroll
      for(int j=0;j<2;j++){ acc[g][i][j][0]=0.f; acc[g][i][j][1]=0.f; acc[g][i][j][2]=0.f; acc[g][i][j][3]=0.f; }
    }
  }

  auto loadrg = [&](int it){
    int kg = it*32 + skc;
    const float* ap = (kg < K1) ? (A1 + (size_t)(row0+sr)*lda1 + kg)
                                : (A2 + (size_t)(row0+sr)*lda2 + (kg-K1));
    float4 v0 = *(const float4*)ap;
    float4 v1 = *(const float4*)(ap+4);
    fa[0]=v0.x; fa[1]=v0.y; fa[2]=v0.z; fa[3]=v0.w;
    fa[4]=v1.x; fa[5]=v1.y; fa[6]=v1.z; fa[7]=v1.w;
    int cb = col0 + sr;
    #pragma unroll
    for(int g=0;g<3;g++)
      bregs[g] = *(const s8v*)(BT + (size_t)(g*Hd + cb)*ldbt + kg);
  };
  auto writeb = [&](int buf){
    s8v av;
    #pragma unroll
    for(int j=0;j<8;j++) av[j] = (short)f2bf(fa[j]);
    *(s8v*)&As[buf][sr][skc] = av;
    #pragma unroll
    for(int g=0;g<3;g++) *(s8v*)&Bs[buf][g][sr][skc] = bregs[g];
  };

  loadrg(0); writeb(0);
  __syncthreads();
  for(int it=0; it<nk; ++it){
    int cur = it & 1;
    bool more = (it+1) < nk;
    if(more) loadrg(it+1);
    const int fr = lane & 15, fk = (lane >> 4) * 8;
    s8v a0 = *(const s8v*)&As[cur][wr*32      + fr][fk];
    s8v a1 = *(const s8v*)&As[cur][wr*32 + 16 + fr][fk];
    #pragma unroll
    for(int g=0;g<3;g++){
      s8v b0 = *(const s8v*)&Bs[cur][g][wc*32      + fr][fk];
      s8v b1 = *(const s8v*)&Bs[cur][g][wc*32 + 16 + fr][fk];
      acc[g][0][0] = __builtin_amdgcn_mfma_f32_16x16x32_bf16(a0,b0,acc[g][0][0],0,0,0);
      acc[g][0][1] = __builtin_amdgcn_mfma_f32_16x16x32_bf16(a0,b1,acc[g][0][1],0,0,0);
      acc[g][1][0] = __builtin_amdgcn_mfma_f32_16x16x32_bf16(a1,b0,acc[g][1][0],0,0,0);
      acc[g][1][1] = __builtin_amdgcn_mfma_f32_16x16x32_bf16(a1,b1,acc[g][1][1],0,0,0);
    }
    if(more) writeb(cur^1);
    __syncthreads();
  }

  const int fr = lane & 15, fq = lane >> 4;
  #pragma unroll
  for(int fi=0; fi<2; fi++){
    #pragma unroll
    for(int fj=0; fj<2; fj++){
      int col = col0 + wc*32 + fj*16 + fr;
      #pragma unroll
      for(int r=0;r<4;r++){
        int row = row0 + wr*32 + fi*16 + fq*4 + r;
        float v[3];
        #pragma unroll
        for(int g=0;g<3;g++){
          float x = acc[g][fi][fj][r];
          if(Cadd) x += Cadd[(size_t)row*ldcadd + g*Hd + col];
          if(bias) x += bias[g*Hd + col];
          v[g] = x;
        }
        const float* ghr = GHp + (size_t)row*ldgh;
        float g0 = ghr[col], g1 = ghr[Hd+col], g2 = ghr[2*Hd+col];
        float r_ = sig_(v[0] + g0);
        float u_ = sig_(v[1] + g1);
        float n_ = tanhf(fmaf(r_, g2, v[2]));
        size_t hi = (size_t)row*Hd + col;
        float h = Hp[hi];
        Hp[hi] = (1.f-u_)*n_ + u_*h;
      }
    }
  }
}

// ===================== fp32 vector GEMM (SAFE fallback) =====================
template<int BM>
__global__ __launch_bounds__(256)
void gemm_k(const float* __restrict__ A1, int lda1, int K1,
            const float* __restrict__ A2, int lda2, int K2,
            const float* __restrict__ Bm, int ldb,
            const float* __restrict__ bias,
            const float* __restrict__ Cadd, int rowmask, int ldcadd,
            float* __restrict__ Cm, int ldc, int N, int relu_cut)
{
  constexpr int BN = 64, BK = 32;
  constexpr int TM = BM/16;
  constexpr int PAD = (BM>=32) ? 4 : 1;
  __shared__ float As[BK][BM+PAD];
  __shared__ float Bs[BK][BN];
  const int tid = threadIdx.x;
  const int row0 = blockIdx.y * BM;
  const int col0 = blockIdx.x * BN;
  const int tx = tid & 15, ty = tid >> 4;
  float4 acc[TM];
  #pragma unroll
  for(int i=0;i<TM;i++) acc[i] = make_float4(0.f,0.f,0.f,0.f);
  const int Kt = K1 + K2;
  for(int k0=0; k0<Kt; k0+=BK){
    if constexpr (BM>=32){
      #pragma unroll
      for(int j=0;j<BM/32;j++){
        int ci = tid + j*256;
        int r  = ci >> 3;
        int kq = ci & 7;
        int kg = k0 + kq*4;
        const float* ap = (kg < K1) ? (A1 + (size_t)(row0+r)*lda1 + kg)
                                    : (A2 + (size_t)(row0+r)*lda2 + (kg-K1));
        float4 v = *(const float4*)ap;
        As[kq*4+0][r]=v.x; As[kq*4+1][r]=v.y; As[kq*4+2][r]=v.z; As[kq*4+3][r]=v.w;
      }
    } else {
      int r  = tid >> 4;
      int kq = tid & 15;
      int kg = k0 + kq*2;
      const float* ap = (kg < K1) ? (A1 + (size_t)(row0+r)*lda1 + kg)
                                  : (A2 + (size_t)(row0+r)*lda2 + (kg-K1));
      float2 v = *(const float2*)ap;
      As[kq*2+0][r]=v.x; As[kq*2+1][r]=v.y;
    }
    #pragma unroll
    for(int j=0;j<2;j++){
      int ci = tid + j*256;
      int r = ci >> 4, c4 = ci & 15;
      int c = col0 + c4*4;
      float4 v = make_float4(0.f,0.f,0.f,0.f);
      if(c < N) v = *(const float4*)(Bm + (size_t)(k0+r)*ldb + c);
      *(float4*)&Bs[r][c4*4] = v;
    }
    __syncthreads();
    #pragma unroll
    for(int kk=0; kk<BK; kk++){
      float4 b = *(const float4*)&Bs[kk][tx*4];
      if constexpr (TM==4){
        float4 a = *(const float4*)&As[kk][ty*4];
        acc[0].x=fmaf(a.x,b.x,acc[0].x); acc[0].y=fmaf(a.x,b.y,acc[0].y); acc[0].z=fmaf(a.x,b.z,acc[0].z); acc[0].w=fmaf(a.x,b.w,acc[0].w);
        acc[1].x=fmaf(a.y,b.x,acc[1].x); acc[1].y=fmaf(a.y,b.y,acc[1].y); acc[1].z=fmaf(a.y,b.z,acc[1].z); acc[1].w=fmaf(a.y,b.w,acc[1].w);
        acc[2].x=fmaf(a.z,b.x,acc[2].x); acc[2].y=fmaf(a.z,b.y,acc[2].y); acc[2].z=fmaf(a.z,b.z,acc[2].z); acc[2].w=fmaf(a.z,b.w,acc[2].w);
        acc[3].x=fmaf(a.w,b.x,acc[3].x); acc[3].y=fmaf(a.w,b.y,acc[3].y); acc[3].z=fmaf(a.w,b.z,acc[3].z); acc[3].w=fmaf(a.w,b.w,acc[3].w);
      } else if constexpr (TM==2){
        float2 a = *(const float2*)&As[kk][ty*2];
        acc[0].x=fmaf(a.x,b.x,acc[0].x); acc[0].y=fmaf(a.x,b.y,acc[0].y); acc[0].z=fmaf(a.x,b.z,acc[0].z); acc[0].w=fmaf(a.x,b.w,acc[0].w);
        acc[1].x=fmaf(a.y,b.x,acc[1].x); acc[1].y=fmaf(a.y,b.y,acc[1].y); acc[1].z=fmaf(a.y,b.z,acc[1].z); acc[1].w=fmaf(a.y,b.w,acc[1].w);
      } else {
        float a = As[kk][ty];
        acc[0].x=fmaf(a,b.x,acc[0].x); acc[0].y=fmaf(a,b.y,acc[0].y); acc[0].z=fmaf(a,b.z,acc[0].z); acc[0].w=fmaf(a,b.w,acc[0].w);
      }
    }
    __syncthreads();
  }
  int c = col0 + tx*4;
  if(c >= N) return;
  #pragma unroll
  for(int i=0;i<TM;i++){
    int r = row0 + ty*TM + i;
    float4 v = acc[i];
    if(Cadd){
      float4 cv = *(const float4*)&Cadd[(size_t)(r & rowmask)*ldcadd + c];
      v.x+=cv.x; v.y+=cv.y; v.z+=cv.z; v.w+=cv.w;
    }
    if(bias){
      float4 bv = *(const float4*)&bias[c];
      v.x+=bv.x; v.y+=bv.y; v.z+=bv.z; v.w+=bv.w;
    }
    if(c < relu_cut){
      v.x=fmaxf(v.x,0.f); v.y=fmaxf(v.y,0.f); v.z=fmaxf(v.z,0.f); v.w=fmaxf(v.w,0.f);
    }
    *(float4*)&Cm[(size_t)r*ldc + c] = v;
  }
}

// ===================== weight conversion / packing =====================
__global__ void k_cvtT(const float* __restrict__ W, ushort_t* __restrict__ WT,
                       int K, int N){
  int i = blockIdx.x*256 + threadIdx.x;
  if(i >= K*N) return;
  int k = i / N, n = i % N;
  WT[(size_t)n*K + k] = f2bf(W[i]);
}
__global__ void k_packT1(const float* __restrict__ We1, const float* __restrict__ Wp1,
                         const float* __restrict__ Wh1, ushort_t* __restrict__ WB1T){
  int i = blockIdx.x*256 + threadIdx.x;
  if(i >= 2560*1024) return;
  int n = i >> 10, k = i & 1023;
  float v;
  if(n < 512)       v = We1[(size_t)k*512 + n];
  else if(n < 1024) v = (k<512) ? Wp1[(size_t)k*512 + (n-512)] : 0.f;
  else              v = (k<512) ? Wh1[(size_t)k*1536 + (n-1024)] : 0.f;
  WB1T[i] = f2bf(v);
}
__global__ void k_packT2(const float* __restrict__ We2, const float* __restrict__ Wp2,
                         ushort_t* __restrict__ WB2T,
                         const float* __restrict__ be1, const float* __restrict__ bp1,
                         const float* __restrict__ bh1, float* __restrict__ bb1,
                         const float* __restrict__ be2, const float* __restrict__ bp2,
                         float* __restrict__ bb2){
  int i = blockIdx.x*256 + threadIdx.x;
  if(i < 512*1024){
    int n = i >> 10, k = i & 1023;
    float v = 0.f;
    if(n < 256 && k < 512)        v = We2[(size_t)k*256 + n];
    else if(n >= 256 && k >= 512) v = Wp2[(size_t)(k-512)*256 + (n-256)];
    WB2T[i] = f2bf(v);
  }
  if(i < 2560) bb1[i] = (i<512)? be1[i] : (i<1024)? bp1[i-512] : bh1[i-1024];
  if(i < 512)  bb2[i] = (i<256)? be2[i] : bp2[i-256];
}

// ===================== elementwise / reduction kernels =====================
__global__ void k_init(float* S, float* sym){
  int t=threadIdx.x; if(t<5) S[t]=0.f; if(t<48) sym[t]=0.f;
}
__global__ void k_copy(const float* __restrict__ s, float* __restrict__ d, int n4){
  int i=blockIdx.x*blockDim.x+threadIdx.x;
  if(i<n4) ((float4*)d)[i]=((const float4*)s)[i];
}
__global__ void k_kldzt(const float* __restrict__ encp, int lde,
                        const float* __restrict__ prip, int ldp,
                        const float* __restrict__ eps, float* __restrict__ zt,
                        float* kacc, int B_, int Z_){
  float loc=0.f;
  int n = B_*Z_;
  for(int i=blockIdx.x*blockDim.x+threadIdx.x; i<n; i+=gridDim.x*blockDim.x){
    int b=i/Z_, cidx=i%Z_;
    float m1=encp[(size_t)b*lde+cidx], m2=prip[(size_t)b*ldp+cidx];
    float s1=sp_(m1), s2=sp_(m2);
    loc += kld_(m1,s1,m2,s2);
    zt[i] = fmaf(eps[i], s1, m1);
  }
  loc = blockReduceSum(loc);
  if(threadIdx.x==0) atomicAdd(kacc, 0.5f*loc);
}
__global__ void k_expand(const float* __restrict__ mean, const float* __restrict__ eps,
                         float* __restrict__ out, int per, int total){
  int i = blockIdx.x*blockDim.x+threadIdx.x;
  if(i<total){
    float m = mean[i % per];
    out[i] = fmaf(eps[i], sp_(m), m);
  }
}
__global__ void k_sym(const float* __restrict__ om, const float* __restrict__ en,
                      float* sym, int n){
  int a = blockIdx.y;
  const float* e = en + (size_t)a*n;
  float loc=0.f;
  for(int i=blockIdx.x*blockDim.x+threadIdx.x; i<n; i+=gridDim.x*blockDim.x){
    float m1=om[i], m2=e[i];
    float s1=sp_(m1), s2=sp_(m2);
    float d=m1-m2, d2=d*d, q1=s1*s1, q2=s2*s2;
    loc += (q1+d2)/q2 + (q2+d2)/q1 - 2.f;
  }
  loc = blockReduceSum(loc);
  if(threadIdx.x==0) atomicAdd(&sym[a], 0.5f*loc);
}
__global__ void k_argmin(const float* sym, int n, int* jsel, float* dis, int add){
  if(threadIdx.x==0 && blockIdx.x==0){
    float m=sym[0]; int j=0;
    for(int a=1;a<n;a++) if(sym[a]<m){m=sym[a];j=a;}
    *jsel=j;
    if(add) *dis += m; else *dis = m;
  }
}
__global__ void k_kldsel(const float* __restrict__ en, const float* __restrict__ pn,
                         const int* jsel, int per, float* out){
  size_t base = (size_t)(*jsel)*per;
  float loc=0.f;
  for(int i=blockIdx.x*blockDim.x+threadIdx.x; i<per; i+=gridDim.x*blockDim.x){
    float m1=en[base+i], m2=pn[base+i];
    loc += kld_(m1, sp_(m1), m2, sp_(m2));
  }
  loc=blockReduceSum(loc);
  if(threadIdx.x==0) atomicAdd(out, 0.5f*loc);
}
__global__ void k_gather(const float* __restrict__ src, const int* jsel,
                         float* __restrict__ dst, int per){
  int i=blockIdx.x*blockDim.x+threadIdx.x;
  if(i<per) dst[i]=src[(size_t)(*jsel)*per+i];
}
__global__ void k_gru(const float* __restrict__ gi, int ldgi,
                      const float* __restrict__ gh, int ldgh,
                      float* __restrict__ h, int B_, int H_){
  int i=blockIdx.x*blockDim.x+threadIdx.x;
  if(i<B_*H_){
    int b=i/H_, c=i%H_;
    const float* gib=gi+(size_t)b*ldgi;
    const float* ghb=gh+(size_t)b*ldgh;
    float r=sig_(gib[c]+ghb[c]);
    float u=sig_(gib[H_+c]+ghb[H_+c]);
    float nn=tanhf(fmaf(r, ghb[2*H_+c], gib[2*H_+c]));
    h[i]=(1.f-u)*nn + u*h[i];
  }
}

extern "C" void kernel_launch(void* const* d_in, const int* in_sizes, int n_in,
                              void* d_out, int out_size, void* d_ws, size_t ws_size,
                              hipStream_t stream)
{
  const int T=32, B=512, F=512, H=512, Z=256, G=3, A=10, C=1000;
  const float* feat   = (const float*)d_in[0];
  const float* h0     = (const float*)d_in[1];
  const float* eps_z  = (const float*)d_in[2];
  const float* eps_g  = (const float*)d_in[3];
  const float* eps_n  = (const float*)d_in[4];
  const float* eps_f  = (const float*)d_in[5];
  const float* Wpx=(const float*)d_in[6],  *bpx=(const float*)d_in[7];
  const float* Wenc1=(const float*)d_in[8],*benc1=(const float*)d_in[9];
  const float* Wenc2=(const float*)d_in[10],*benc2=(const float*)d_in[11];
  const float* Wpr1=(const float*)d_in[12],*bpr1=(const float*)d_in[13];
  const float* Wpr2=(const float*)d_in[14],*bpr2=(const float*)d_in[15];
  const float* Wpz=(const float*)d_in[16], *bpz=(const float*)d_in[17];
  const float* Wih1=(const float*)d_in[18],*Whh1=(const float*)d_in[19];
  const float* bih1=(const float*)d_in[20],*bhh1=(const float*)d_in[21];
  const float* Wzn=(const float*)d_in[22], *bzn=(const float*)d_in[23];
  const float* Wprn1=(const float*)d_in[24],*bprn1=(const float*)d_in[25];
  const float* Wprn2=(const float*)d_in[26],*bprn2=(const float*)d_in[27];
  const float* Wga=(const float*)d_in[28], *bga=(const float*)d_in[29];
  const float* Woa1=(const float*)d_in[30],*boa1=(const float*)d_in[31];
  const float* Woa2=(const float*)d_in[32],*boa2=(const float*)d_in[33];
  const float* Wna1=(const float*)d_in[34],*bna1=(const float*)d_in[35];
  const float* Wna2=(const float*)d_in[36],*bna2=(const float*)d_in[37];
  const float* Wen=(const float*)d_in[38], *ben=(const float*)d_in[39];
  const float* Wact=(const float*)d_in[40],*bact=(const float*)d_in[41];
  const float* Wih2=(const float*)d_in[42],*Whh2=(const float*)d_in[43];
  const float* bih2=(const float*)d_in[44],*bhh2=(const float*)d_in[45];
  const float* Wcc=(const float*)d_in[46], *bcc=(const float*)d_in[47];
  const float* Wnc=(const float*)d_in[48], *bnc=(const float*)d_in[49];

  float* ws = (float*)d_ws;
  size_t off = 0;
  auto alloc = [&](size_t n){ float* p = ws + off; off += n; return p; };
  // ---- base fp32 buffers ----
  float* Hb  = alloc((size_t)B*H);
  float* E1  = alloc((size_t)B*H);
  float* P1  = alloc((size_t)B*H);
  float* ZP  = alloc((size_t)B*H);
  float* NM  = alloc((size_t)B*H);
  float* OA  = alloc((size_t)B*H);
  float* PAb = alloc((size_t)B*H);
  float* CAb = alloc((size_t)B*H);
  float* GI  = alloc((size_t)B*3*H);   // safe path only
  float* GH  = alloc((size_t)B*3*H);
  float* ENC = alloc((size_t)B*Z);
  float* PRI = alloc((size_t)B*Z);
  float* ZT  = alloc((size_t)B*Z);
  float* OM  = alloc((size_t)B*Z);
  float* PNH = alloc((size_t)B*Z);
  float* OAZ = alloc((size_t)B*Z);
  float* BASE= alloc((size_t)B*Z);
  float* NACT= alloc((size_t)A*B*H);
  float* PMID= alloc((size_t)A*B*H);
  float* PNX = alloc((size_t)A*B*Z);
  float* ENCN= alloc((size_t)A*B*Z);
  float* BUFA= alloc((size_t)B*H);
  float* BUFB= alloc((size_t)B*H);
  float* BUFC= alloc((size_t)B*H);
  float* C1  = alloc((size_t)B*2560);
  float* C2  = alloc((size_t)B*512);
  float* bb1 = alloc(2560);
  float* bb2 = alloc(512);
  float* SYM = alloc(16);
  float* SYMF0 = alloc(16);
  float* SYMF1 = alloc(16);
  int*   JSEL = (int*)alloc(16);
  // ---- bf16 weight arena (FAST tier) ----
  size_t mark = off;
  auto ua = [&](size_t n){ ushort_t* p = (ushort_t*)(ws + off); off += (n+1)/2; return p; };
  ushort_t* WpxT  = ua((size_t)512*512);
  ushort_t* WB1T  = ua((size_t)2560*1024);
  ushort_t* WB2T  = ua((size_t)512*1024);
  ushort_t* WpzT  = ua((size_t)512*256);
  ushort_t* Wih1T = ua((size_t)1536*1024);
  ushort_t* Wpr1T = ua((size_t)512*512);
  ushort_t* Wpr2T = ua((size_t)256*512);
  ushort_t* Wprn1T= ua((size_t)512*512);
  ushort_t* Wprn2T= ua((size_t)256*512);
  ushort_t* WznT  = ua((size_t)512*256);
  ushort_t* WgaT  = ua((size_t)512*768);
  ushort_t* Woa1T = ua((size_t)512*512);
  ushort_t* Woa2T = ua((size_t)256*512);
  ushort_t* Wna1T = ua((size_t)512*512);
  ushort_t* Wna2T = ua((size_t)256*512);
  ushort_t* WenT  = ua((size_t)256*512);
  ushort_t* WactT = ua((size_t)512*512);
  ushort_t* Wih2T = ua((size_t)1536*1024);
  ushort_t* Whh2T = ua((size_t)1536*512);
  ushort_t* WccT  = ua((size_t)1000*512);
  ushort_t* WncT  = ua((size_t)1000*512);
  bool fast = off*4 <= ws_size;
  if(!fast) off = mark;
  // ---- PHIX tier ----
  size_t mark2 = off;
  float* PHIX = alloc((size_t)T*B*H);
  bool bigphix = off*4 <= ws_size;
  float* XP = nullptr;
  if(!bigphix){ off = mark2; XP = alloc((size_t)B*H); PHIX = nullptr; }
  // ---- precompute tier (GIX/C1X) ----
  size_t mark3 = off;
  float* C1X = alloc((size_t)T*B*512);
  float* GIX = alloc((size_t)T*B*1536);
  bool bigpre = fast && bigphix && (off*4 <= ws_size);
  if(!bigpre) off = mark3;

  float* outCur = (float*)d_out;
  float* outFut = outCur + (size_t)B*C;
  float* S      = outCur + (size_t)B*C*4;

  auto ew = [&](int n){ return dim3((n+255)/256); };
  auto cvt = [&](const float* W, ushort_t* WT, int K, int N){
    k_cvtT<<<(K*N+255)/256,256,0,stream>>>(W,WT,K,N);
  };
  auto mf = [&](const float* A1,int lda1,int K1,
                const float* A2,int lda2,int K2,
                const ushort_t* BT,int ldbt, const float* bias,
                const float* Cadd,int rowmask,int ldcadd,int cadd_cols,
                float* Cm,int ldc,int M,int N,int cut,
                const float* epsP, float* kldS){
    dim3 g((N+63)/64, M/64);
    gemm_mf<<<g,256,0,stream>>>(A1,lda1,K1, A2?A2:A1,lda2,K2, BT,ldbt,bias,
                                Cadd,rowmask,ldcadd,cadd_cols, Cm,ldc,N,cut, epsP,kldS);
  };
  auto mgru = [&](const float* A1,int lda1,int K1,
                  const float* A2,int lda2,int K2,
                  const ushort_t* BT,int ldbt, const float* bias,
                  const float* Cadd,int ldcadd,
                  const float* GHp,int ldgh, float* Hp,int M,int Hd){
    dim3 g(Hd/64, M/64);
    gemm_gru<<<g,256,0,stream>>>(A1,lda1,K1, A2?A2:A1,lda2,K2, BT,ldbt,bias,
                                 Cadd,ldcadd, GHp,ldgh, Hp,Hd);
  };
  auto gemm = [&](const float* A1,int lda1,int K1,
                  const float* A2,int lda2,int K2,
                  const float* Bw,int ldb, const float* bias,
                  const float* Cadd,int rowmask,int ldcadd,
                  float* Cm,int ldc,int M,int N,int relu){
    int nb = (N+63)/64;
    int cut = relu ? N : 0;
    if(M%64==0 && (M/64)*nb >= 160){
      dim3 g(nb, M/64);
      gemm_k<64><<<g,256,0,stream>>>(A1,lda1,K1, A2?A2:A1,lda2,K2, Bw,ldb,bias,
                                     Cadd,rowmask,ldcadd, Cm,ldc,N,cut);
    } else if(M%32==0 && (M/32)*nb >= 96){
      dim3 g(nb, M/32);
      gemm_k<32><<<g,256,0,stream>>>(A1,lda1,K1, A2?A2:A1,lda2,K2, Bw,ldb,bias,
                                     Cadd,rowmask,ldcadd, Cm,ldc,N,cut);
    } else {
      dim3 g(nb, M/16);
      gemm_k<16><<<g,256,0,stream>>>(A1,lda1,K1, A2?A2:A1,lda2,K2, Bw,ldb,bias,
                                     Cadd,rowmask,ldcadd, Cm,ldc,N,cut);
    }
  };

  k_init<<<1,64,0,stream>>>(S, SYM);
  k_copy<<<ew(B*H/4),256,0,stream>>>(h0, Hb, B*H/4);

  if(fast){
    // ---- one-time weight conversion ----
    cvt(Wpx, WpxT, 512, 512);
    k_packT1<<<(2560*1024+255)/256,256,0,stream>>>(Wenc1,Wpr1,Whh1,WB1T);
    k_packT2<<<(512*1024+255)/256,256,0,stream>>>(Wenc2,Wpr2,WB2T, benc1,bpr1,bhh1,bb1, benc2,bpr2,bb2);
    cvt(Wpz,  WpzT, 256, 512);
    cvt(Wih1, Wih1T,1024,1536);
    cvt(Wpr1, Wpr1T, 512, 512);
    cvt(Wpr2, Wpr2T, 512, 256);
    cvt(Wprn1,Wprn1T,512, 512);
    cvt(Wprn2,Wprn2T,512, 256);
    cvt(Wzn,  WznT,  256, 512);
    cvt(Wga,  WgaT,  768, 512);
    cvt(Woa1, Woa1T, 512, 512);
    cvt(Woa2, Woa2T, 512, 256);
    cvt(Wna1, Wna1T, 512, 512);
    cvt(Wna2, Wna2T, 512, 256);
    cvt(Wen,  WenT,  512, 256);
    cvt(Wact, WactT, 512, 512);
    cvt(Wih2, Wih2T,1024,1536);
    cvt(Whh2, Whh2T, 512,1536);
    cvt(Wcc,  WccT,  512,1000);
    cvt(Wnc,  WncT,  512,1000);

    if(bigphix)
      mf(feat,F,F, 0,0,0, WpxT,512, bpx, 0,0,0,0, PHIX,H, T*B,H, H, 0,0);
    if(bigpre){
      // C1X = phix @ Wenc1[512:1024]   (xp contribution to enc hidden)
      mf(PHIX,H,H, 0,0,0, WB1T+512,1024, 0, 0,0,0,0, C1X,512, T*B,512, 0, 0,0);
      // GIX = phix @ Wih1[0:512] + bih1
      mf(PHIX,H,H, 0,0,0, Wih1T,1024, bih1, 0,0,0,0, GIX,1536, T*B,1536, 0, 0,0);
    }

    // ---- scan: 4 dispatches per step ----
    for(int t=0;t<T;t++){
      const float* xp;
      if(bigphix) xp = PHIX + (size_t)t*B*H;
      else { mf(feat+(size_t)t*B*F,F,F, 0,0,0, WpxT,512, bpx, 0,0,0,0, XP,H, B,H, H, 0,0); xp = XP; }
      const float* epz = eps_z + (size_t)t*B*Z;
      if(bigpre){
        mf(Hb,H,H, 0,0,0, WB1T,1024, bb1,
           C1X+(size_t)t*B*512, B-1, 512, 512, C1,2560, B,2560, 1024, 0,0);
      } else {
        mf(Hb,H,H, xp,H,H, WB1T,1024, bb1, 0,0,0,0, C1,2560, B,2560, 1024, 0,0);
      }
      mf(C1,2560,1024, 0,0,0, WB2T,1024, bb2, 0,0,0,0, C2,512, B,512, 0, 0,0);
      // ZP = relu(zt @ Wpz + bpz) with zt computed on the fly; KLD folded in
      mf(C2,512,256, 0,0,0, WpzT,256, bpz, 0,0,0,0, ZP,H, B,H, H, epz, &S[0]);
      if(bigpre){
        mgru(ZP,H,H, 0,0,0, Wih1T+512,1024, 0,
             GIX+(size_t)t*B*1536, 1536, C1+1024, 2560, Hb, B, H);
      } else {
        mgru(xp,H,H, ZP,H,H, Wih1T,1024, bih1, 0,0, C1+1024, 2560, Hb, B, H);
      }
    }

    // ---- phase 3 (only g = G-1 matters) ----
    mf(Hb,H,H, 0,0,0, Wpr1T,512, bpr1, 0,0,0,0, P1,H, B,H, H, 0,0);
    mf(P1,H,H, 0,0,0, Wpr2T,512, bpr2, 0,0,0,0, OM,Z, B,Z, 0, 0,0);
    mf(Hb,H,H, 0,0,0, Wprn1T,512, bprn1, 0,0,0,0, P1,H, B,H, H, 0,0);
    mf(P1,H,H, 0,0,0, Wprn2T,512, bprn2, 0,0,0,0, PNH,Z, B,Z, 0, 0,0);
    k_expand<<<ew(B*Z),256,0,stream>>>(OM, eps_g+(size_t)(G-1)*B*Z, ZT, B*Z, B*Z);
    mf(ZT,Z,Z, 0,0,0, WznT,256, bzn, 0,0,0,0, E1,H, B,H, H, 0,0);
    mf(E1,H,H, PNH,Z,Z, WgaT,768, bga, 0,0,0,0, OA,H, B,H, H, 0,0);
    mf(PNH,Z,Z, OA,H,H, WgaT,768, bga, 0,0,0,0, NM,H, B,H, H, 0,0);
    k_expand<<<ew(A*B*H),256,0,stream>>>(NM, eps_n+(size_t)(G-1)*A*B*H, NACT, B*H, A*B*H);
    mf(NACT,H,H, 0,0,0, Wna1T,512, bna1, 0,0,0,0, PMID,H, A*B,H, H, 0,0);
    mf(PMID,H,H, 0,0,0, Wna2T,512, bna2, 0,0,0,0, PNX,Z, A*B,Z, 0, 0,0);
    mf(OA,H,H, 0,0,0, Woa1T,512, boa1, 0,0,0,0, P1,H, B,H, H, 0,0);
    mf(P1,H,H, 0,0,0, Woa2T,512, boa2, 0,0,0,0, OAZ,Z, B,Z, 0, 0,0);
    mf(OAZ,Z,Z, 0,0,0, WenT+256,512, ben, 0,0,0,0, BASE,Z, B,Z, 0, 0,0);
    mf(PNX,Z,Z, 0,0,0, WenT,512, 0, BASE,B-1,Z,Z, ENCN,Z, A*B,Z, Z, 0,0);
    k_sym<<<dim3(32,A),256,0,stream>>>(OM, ENCN, SYM, B*Z);
    k_argmin<<<1,64,0,stream>>>(SYM, A, &JSEL[0], &S[2], 0);
    k_kldsel<<<128,256,0,stream>>>(ENCN, PNX, &JSEL[0], B*Z, &S[1]);
    k_gather<<<ew(B*H),256,0,stream>>>(NACT, &JSEL[0], BUFA, B*H);

    // ---- phase 4 ----
    const float* pre = OA; const float* cur = BUFA;
    float* futbuf[2] = {BUFB, BUFC};
    for(int i=0;i<2;i++){
      mf(pre,H,H, 0,0,0, WactT,512, bact, 0,0,0,0, PAb,H, B,H, H, 0,0);
      mf(cur,H,H, 0,0,0, WactT,512, bact, 0,0,0,0, CAb,H, B,H, H, 0,0);
      mf(Hb,H,H, 0,0,0, Whh2T,512, bhh2, 0,0,0,0, GH,3*H, B,3*H, 0, 0,0);
      mgru(PAb,H,H, CAb,H,H, Wih2T,1024, bih2, 0,0, GH,3*H, Hb, B, H);
      pre = cur;
      mf(Hb,H,H, 0,0,0, Wprn1T,512, bprn1, 0,0,0,0, P1,H, B,H, H, 0,0);
      mf(P1,H,H, 0,0,0, Wprn2T,512, bprn2, 0,0,0,0, PNH,Z, B,Z, 0, 0,0);
      mf(PNH,Z,Z, pre,H,H, WgaT,768, bga, 0,0,0,0, NM,H, B,H, H, 0,0);
      k_expand<<<ew(A*B*H),256,0,stream>>>(NM, eps_f+(size_t)i*A*B*H, NACT, B*H, A*B*H);
      mf(NACT,H,H, 0,0,0, Wna1T,512, bna1, 0,0,0,0, PMID,H, A*B,H, H, 0,0);
      mf(PMID,H,H, 0,0,0, Wna2T,512, bna2, 0,0,0,0, PNX,Z, A*B,Z, 0, 0,0);
      mf(pre,H,H, 0,0,0, Wna1T,512, bna1, 0,0,0,0, P1,H, B,H, H, 0,0);
      mf(P1,H,H, 0,0,0, Wna2T,512, bna2, 0,0,0,0, OAZ,Z, B,Z, 0, 0,0);
      mf(OAZ,Z,Z, 0,0,0, WenT+256,512, ben, 0,0,0,0, BASE,Z, B,Z, 0, 0,0);
      mf(PNX,Z,Z, 0,0,0, WenT,512, 0, BASE,B-1,Z,Z, ENCN,Z, A*B,Z, Z, 0,0);
      float* symf = (i==0)?SYMF0:SYMF1;
      k_sym<<<dim3(32,A),256,0,stream>>>(OM, ENCN, symf, B*Z);
      k_argmin<<<1,64,0,stream>>>(symf, A, &JSEL[1+i], &S[4], 1);
      k_kldsel<<<128,256,0,stream>>>(ENCN, PNX, &JSEL[1+i], B*Z, &S[3]);
      k_gather<<<ew(B*H),256,0,stream>>>(NACT, &JSEL[1+i], futbuf[i], B*H);
      cur = futbuf[i];
    }
    mf(OA,H,H, 0,0,0, WccT,512, bcc, 0,0,0,0, outCur,C, B,C, 0, 0,0);
    mf(BUFA,H,H, 0,0,0, WncT,512, bnc, 0,0,0,0, outFut,C, 3*B,C, 0, 0,0);
    return;
  }

  // ======================= SAFE (fp32) PATH =======================
  if(bigphix)
    gemm(feat,F,F, 0,0,0, Wpx,H,bpx, 0,0,0, PHIX,H, T*B,H, 1);
  for(int t=0;t<T;t++){
    const float* xp;
    if(bigphix) xp = PHIX + (size_t)t*B*H;
    else { gemm(feat+(size_t)t*B*F,F,F, 0,0,0, Wpx,H,bpx, 0,0,0, XP,H, B,H, 1); xp = XP; }
    const float* epz = eps_z + (size_t)t*B*Z;
    gemm(Hb,H,H, xp,H,H, Wenc1,H,benc1, 0,0,0, E1,H, B,H, 1);
    gemm(E1,H,H, 0,0,0, Wenc2,Z,benc2, 0,0,0, ENC,Z, B,Z, 0);
    gemm(Hb,H,H, 0,0,0, Wpr1,H,bpr1, 0,0,0, P1,H, B,H, 1);
    gemm(P1,H,H, 0,0,0, Wpr2,Z,bpr2, 0,0,0, PRI,Z, B,Z, 0);
    k_kldzt<<<128,256,0,stream>>>(ENC,Z, PRI,Z, epz, ZT, &S[0], B, Z);
    gemm(ZT,Z,Z, 0,0,0, Wpz,H,bpz, 0,0,0, ZP,H, B,H, 1);
    gemm(xp,H,H, ZP,H,H, Wih1,3*H,bih1, 0,0,0, GI,3*H, B,3*H, 0);
    gemm(Hb,H,H, 0,0,0, Whh1,3*H,bhh1, 0,0,0, GH,3*H, B,3*H, 0);
    k_gru<<<ew(B*H),256,0,stream>>>(GI,3*H, GH,3*H, Hb,B,H);
  }
  gemm(Hb,H,H, 0,0,0, Wpr1,H,bpr1, 0,0,0, P1,H, B,H, 1);
  gemm(P1,H,H, 0,0,0, Wpr2,Z,bpr2, 0,0,0, OM,Z, B,Z, 0);
  gemm(Hb,H,H, 0,0,0, Wprn1,H,bprn1, 0,0,0, P1,H, B,H, 1);
  gemm(P1,H,H, 0,0,0, Wprn2,Z,bprn2, 0,0,0, PNH,Z, B,Z, 0);
  k_expand<<<ew(B*Z),256,0,stream>>>(OM, eps_g+(size_t)(G-1)*B*Z, ZT, B*Z, B*Z);
  gemm(ZT,Z,Z, 0,0,0, Wzn,H,bzn, 0,0,0, E1,H, B,H, 1);
  gemm(E1,H,H, PNH,Z,Z, Wga,H,bga, 0,0,0, OA,H, B,H, 1);
  gemm(PNH,Z,Z, OA,H,H, Wga,H,bga, 0,0,0, NM,H, B,H, 1);
  k_expand<<<ew(A*B*H),256,0,stream>>>(NM, eps_n+(size_t)(G-1)*A*B*H, NACT, B*H, A*B*H);
  gemm(NACT,H,H, 0,0,0, Wna1,H,bna1, 0,0,0, PMID,H, A*B,H, 1);
  gemm(PMID,H,H, 0,0,0, Wna2,Z,bna2, 0,0,0, PNX,Z, A*B,Z, 0);
  gemm(OA,H,H, 0,0,0, Woa1,H,boa1, 0,0,0, P1,H, B,H, 1);
  gemm(P1,H,H, 0,0,0, Woa2,Z,boa2, 0,0,0, OAZ,Z, B,Z, 0);
  gemm(OAZ,Z,Z, 0,0,0, Wen+(size_t)Z*Z,Z, ben, 0,0,0, BASE,Z, B,Z, 0);
  gemm(PNX,Z,Z, 0,0,0, Wen,Z, 0, BASE,B-1,Z, ENCN,Z, A*B,Z, 1);
  k_sym<<<dim3(32,A),256,0,stream>>>(OM, ENCN, SYM, B*Z);
  k_argmin<<<1,64,0,stream>>>(SYM, A, &JSEL[0], &S[2], 0);
  k_kldsel<<<128,256,0,stream>>>(ENCN, PNX, &JSEL[0], B*Z, &S[1]);
  k_gather<<<ew(B*H),256,0,stream>>>(NACT, &JSEL[0], BUFA, B*H);
  const float* pre = OA; const float* cur = BUFA;
  float* futbuf[2] = {BUFB, BUFC};
  for(int i=0;i<2;i++){
    gemm(pre,H,H, 0,0,0, Wact,H,bact, 0,0,0, PAb,H, B,H, 1);
    gemm(cur,H,H, 0,0,0, Wact,H,bact, 0,0,0, CAb,H, B,H, 1);
    gemm(PAb,H,H, CAb,H,H, Wih2,3*H,bih2, 0,0,0, GI,3*H, B,3*H, 0);
    gemm(Hb,H,H, 0,0,0, Whh2,3*H,bhh2, 0,0,0, GH,3*H, B,3*H, 0);
    k_gru<<<ew(B*H),256,0,stream>>>(GI,3*H, GH,3*H, Hb,B,H);
    pre = cur;
    gemm(Hb,H,H, 0,0,0, Wprn1,H,bprn1, 0,0,0, P1,H, B,H, 1);
    gemm(P1,H,H, 0,0,0, Wprn2,Z,bprn2, 0,0,0, PNH,Z, B,Z, 0);
    gemm(PNH,Z,Z, pre,H,H, Wga,H,bga, 0,0,0, NM,H, B,H, 1);
    k_expand<<<ew(A*B*H),256,0,stream>>>(NM, eps_f+(size_t)i*A*B*H, NACT, B*H, A*B*H);
    gemm(NACT,H,H, 0,0,0, Wna1,H,bna1, 0,0,0, PMID,H, A*B,H, 1);
    gemm(PMID,H,H, 0,0,0, Wna2,Z,bna2, 0,0,0, PNX,Z, A*B,Z, 0);
    gemm(pre,H,H, 0,0,0, Wna1,H,bna1, 0,0,0, P1,H, B,H, 1);
    gemm(P1,H,H, 0,0,0, Wna2,Z,bna2, 0,0,0, OAZ,Z, B,Z, 0);
    gemm(OAZ,Z,Z, 0,0,0, Wen+(size_t)Z*Z,Z, ben, 0,0,0, BASE,Z, B,Z, 0);
    gemm(PNX,Z,Z, 0,0,0, Wen,Z, 0, BASE,B-1,Z, ENCN,Z, A*B,Z, 1);
    float* symf = (i==0)?SYMF0:SYMF1;
    k_sym<<<dim3(32,A),256,0,stream>>>(OM, ENCN, symf, B*Z);
    k_argmin<<<1,64,0,stream>>>(symf, A, &JSEL[1+i], &S[4], 1);
    k_kldsel<<<128,256,0,stream>>>(ENCN, PNX, &JSEL[1+i], B*Z, &S[3]);
    k_gather<<<ew(B*H),256,0,stream>>>(NACT, &JSEL[1+i], futbuf[i], B*H);
    cur = futbuf[i];
  }
  gemm(OA,H,H, 0,0,0, Wcc,C,bcc, 0,0,0, outCur,C, B,C, 0);
  gemm(BUFA,H,H, 0,0,0, Wnc,C,bnc, 0,0,0, outFut,C, 3*B,C, 0);
}